// Round 15
// baseline (63.029 us; speedup 1.0000x reference)
//
#include <hip/hip_runtime.h>
#include <hip/hip_bf16.h>

// Problem constants (from reference): B=262144, D=256, S=16, C=10.
#define D_DIM 256
#define S_SYS 16
#define C_CLS 10
#define BLK   1024                 // 16 waves/block, 1 block/CU (LDS-capped)
                                   // NOTE: 1024-thread block => VGPR must stay <=128
#define GRID  256
#define CPB   128                  // samples per chunk (1024 threads / 8 lanes-per-sample)

// LDS W layout (UNCHANGED from R9/R12):
//   u32 = 2 packed f16 (dims d, d+1)
//   slot(s, c, q, v) = s*S_STR + c*C_STR + q*L_STR + v   (v = 0..15 real, 16..19 pad)
//   v = 2j + t  ->  weight u32 for dims  j*32 + q*4 + 2t .. +1
// Per-lane, per-class: 16 CONTIGUOUS u32 -> 4x ds_read_b128; each 8-lane group's
// starts (20q mod 32) cover all 32 banks exactly once -> conflict-free.
//
// R14 post-mortem: issuing x-loads BEFORE the staging copy serialized staging's
// ds_writes behind 36 HBM loads in the in-order vmcnt queue -> barrier delayed
// by full HBM latency -> +4us. R15: keep prep_k (pre-packed W image in d_ws,
// proven correct in R14) + linear uint4 staging, but order = staging loads
// FIRST, then x prefetch, then barrier. Compute loop byte-identical to R12.
#define L_STR 20
#define C_STR 160      // 8 * L_STR
#define S_STR 1604     // C_CLS * C_STR + 4
#define WIMG_U32 (S_SYS * S_STR)   // 25,664 u32 = 102,656 B

typedef __attribute__((ext_vector_type(2))) __fp16 half2v;

__device__ __forceinline__ half2v pack2(float x, float y) {
    return __builtin_amdgcn_cvt_pkrtz(x, y);     // v_cvt_pkrtz_f16_f32
}

__device__ __forceinline__ float fdot2(unsigned w, half2v xp, float c) {
#if __has_builtin(__builtin_amdgcn_fdot2)
    return __builtin_amdgcn_fdot2(__builtin_bit_cast(half2v, w), xp, c, false);
#else
    float d;
    unsigned xu = __builtin_bit_cast(unsigned, xp);
    asm("v_dot2_f32_f16 %0, %1, %2, %3" : "=v"(d) : "v"(w), "v"(xu), "v"(c));
    return d;
#endif
}

// ---- prep: W (f32) -> permuted packed-f16 image in d_ws (identical to R14) ----
__global__ __launch_bounds__(256) void prep_k(const float* __restrict__ W,
                                              unsigned* __restrict__ wimg) {
    const int u = blockIdx.x * 256 + threadIdx.x;       // 0 .. 20479 real slots
    if (u >= S_SYS * C_CLS * 8 * 16) return;
    const int v  = u & 15;
    const int q  = (u >> 4) & 7;
    const int sc = u >> 7;                              // s*10 + c
    const int j  = v >> 1, t = v & 1;
    const float2 f = ((const float2*)W)[(size_t)sc * 128 + j * 16 + q * 2 + t];
    const int s = sc / C_CLS, c = sc - s * C_CLS;
    wimg[s * S_STR + c * C_STR + q * L_STR + v] =
        __builtin_bit_cast(unsigned, pack2(f.x, f.y));
}

__device__ __forceinline__ void load_x(float4 xb[8], const float* __restrict__ x,
                                       long i, int n, int q) {
    const long r = (i < n) ? i : (long)(n - 1);           // clamp (store is masked)
    const float4* p = (const float4*)(x + r * D_DIM) + q; // dims j*32 + q*4 .. +3
    #pragma unroll
    for (int j = 0; j < 8; ++j) xb[j] = p[j * 8];
}

__device__ __forceinline__ int load_sid(const int* __restrict__ sid, long i, int n) {
    return sid[(i < n) ? i : (long)(n - 1)] & (S_SYS - 1);
}

__device__ __forceinline__ void pack_x(half2v xp[16], const float4 xb[8]) {
    #pragma unroll
    for (int j = 0; j < 8; ++j) {
        xp[2 * j]     = pack2(xb[j].x, xb[j].y);
        xp[2 * j + 1] = pack2(xb[j].z, xb[j].w);
    }
}

__device__ __forceinline__ void step_compute(const half2v xp[16], long i, int n, int q, int s,
                                             const unsigned* __restrict__ Wl,
                                             const float* __restrict__ bl,
                                             float* __restrict__ out) {
    const unsigned* wp = Wl + (unsigned)s * S_STR + (unsigned)q * L_STR;

    float acc[C_CLS];
    #pragma unroll
    for (int c = 0; c < C_CLS; ++c) {
        float a = 0.f;
        #pragma unroll
        for (int k = 0; k < 4; ++k) {                     // uint4 = slots v=4k..4k+3
            const uint4 wv = *(const uint4*)&wp[c * C_STR + 4 * k];
            a = fdot2(wv.x, xp[4 * k + 0], a);
            a = fdot2(wv.y, xp[4 * k + 1], a);
            a = fdot2(wv.z, xp[4 * k + 2], a);
            a = fdot2(wv.w, xp[4 * k + 3], a);
        }
        acc[c] = a;
    }

    float v0 = 0.f, v1 = 0.f;
    #pragma unroll
    for (int c = 0; c < C_CLS; ++c) {
        float r = acc[c];
        r += __shfl_xor(r, 1);
        r += __shfl_xor(r, 2);
        r += __shfl_xor(r, 4);
        if (c == q)     v0 = r;   // compile-time c, runtime compare (no scratch)
        if (c == 8 + q) v1 = r;
    }
    if (i < n) {
        float* op = out + i * C_CLS;
        op[q] = v0 + bl[s * C_CLS + q];
        if (q < 2) op[8 + q] = v1 + bl[s * C_CLS + 8 + q];
    }
}

__global__ __launch_bounds__(BLK) void mainf_k(const float* __restrict__ x,
                                               const int* __restrict__ sid,
                                               const unsigned* __restrict__ wimg,
                                               const float* __restrict__ W,   // fallback path
                                               const float* __restrict__ b,
                                               float* __restrict__ out, int n, int use_ws) {
    __shared__ uint4 Wl4[WIMG_U32 / 4];       // 102,656 B, 16B-aligned
    __shared__ float bl[S_SYS * C_CLS];       // 640 B
    unsigned* Wl = (unsigned*)Wl4;

    const int tid = threadIdx.x;
    const int nch = (n + CPB - 1) / CPB;
    const int cpb = (nch + (int)gridDim.x - 1) / (int)gridDim.x;  // chunks per block
    const int c0 = (int)blockIdx.x * cpb;
    const int c1 = (c0 + cpb < nch) ? (c0 + cpb) : nch;
    if (c0 >= c1) return;                     // whole block exits (before any sync)

    // ---- staging FIRST (its loads retire before the x-loads issued below) ----
    if (use_ws) {
        const uint4* __restrict__ src = (const uint4*)wimg;
        #pragma unroll
        for (int t = 0; t < 7; ++t) {
            const int u = tid + t * BLK;
            if (u < WIMG_U32 / 4) Wl4[u] = src[u];
        }
    } else {
        // fallback: in-kernel pack (R12 path), used only if ws too small
        const float2* __restrict__ Wg = (const float2*)W;
        for (int u = tid; u < S_SYS * C_CLS * 8 * 16; u += BLK) {
            const int v  = u & 15;
            const int qq = (u >> 4) & 7;
            const int sc = u >> 7;
            const int j  = v >> 1, t = v & 1;
            const float2 f = Wg[(size_t)sc * 128 + j * 16 + qq * 2 + t];
            const int s = sc / C_CLS, c = sc - s * C_CLS;
            Wl[s * S_STR + c * C_STR + qq * L_STR + v] =
                __builtin_bit_cast(unsigned, pack2(f.x, f.y));
        }
    }
    if (tid < S_SYS * C_CLS) bl[tid] = b[tid];

    const int g = tid >> 3;                   // group (0..127) = sample within chunk
    const int q = tid & 7;                    // lane within group

    // ---- x/sid prefetch AFTER staging issues, BEFORE barrier: the barrier's
    // vmcnt(0) drain then covers useful x-latency instead of idling.
    float4 F0[8], F1[8];
    int s0 = 0, s1 = 0;
    const long i0 = (long)c0 * CPB + g;
    load_x(F0, x, i0, n, q);
    s0 = load_sid(sid, i0, n);
    if (c0 + 1 < c1) {
        const long i1 = (long)(c0 + 1) * CPB + g;
        load_x(F1, x, i1, n, q);
        s1 = load_sid(sid, i1, n);
    }
    __syncthreads();

    // ---- 2-deep pipeline (R12 structure, byte-identical) ----
    half2v P[16];
    int cur = c0;
    while (true) {
        {
            pack_x(P, F0);                               // waits F0's loads
            const long iu = (long)cur * CPB + g;
            const int su = s0;
            const int cn = cur + 2;
            if (cn < c1) {
                const long in2 = (long)cn * CPB + g;
                load_x(F0, x, in2, n, q);
                s0 = load_sid(sid, in2, n);
            }
            step_compute(P, iu, n, q, su, Wl, bl, out);
        }
        if (++cur >= c1) break;

        {
            pack_x(P, F1);                               // waits F1's loads
            const long iu = (long)cur * CPB + g;
            const int su = s1;
            const int cn = cur + 2;
            if (cn < c1) {
                const long in2 = (long)cn * CPB + g;
                load_x(F1, x, in2, n, q);
                s1 = load_sid(sid, in2, n);
            }
            step_compute(P, iu, n, q, su, Wl, bl, out);
        }
        if (++cur >= c1) break;
    }
}

extern "C" void kernel_launch(void* const* d_in, const int* in_sizes, int n_in,
                              void* d_out, int out_size, void* d_ws, size_t ws_size,
                              hipStream_t stream) {
    const float* x = (const float*)d_in[0];
    const int* sid = (const int*)d_in[1];
    const float* W = (const float*)d_in[2];
    const float* b = (const float*)d_in[3];
    float* out = (float*)d_out;
    const int n = in_sizes[1];   // B

    const int use_ws = (ws_size >= (size_t)WIMG_U32 * 4) ? 1 : 0;
    unsigned* wimg = (unsigned*)d_ws;

    if (use_ws) {
        const int nslots = S_SYS * C_CLS * 8 * 16;       // 20480
        prep_k<<<(nslots + 255) / 256, 256, 0, stream>>>(W, wimg);
    }
    mainf_k<<<GRID, BLK, 0, stream>>>(x, sid, wimg, W, b, out, n, use_ws);
}

// Round 16
// 57.590 us; speedup vs baseline: 1.0944x; 1.0944x over previous
//
#include <hip/hip_runtime.h>
#include <hip/hip_bf16.h>

// Problem constants (from reference): B=262144, D=256, S=16, C=10.
// ===== R16 = byte-identical revert to R12 (best measured: 58.0 us) =====
// Falsified levers (each within-session A/B'd):
//   R10: DPP reduce (85us, serialization) -> shfl_xor kept
//   R13: 3-deep pipeline (63us, WAR on shared P buffer) -> 2-deep kept
//   R14: x-loads before staging (62us, in-order vmcnt serialized ds_writes)
//   R15: prep_k + linear staging copy (63us, extra dispatch + lockstep drain)
// Residual over the 44.5us stream floor is structural: LDS-capped 16 waves/CU
// streaming at ~80% of achievable BW + launch/tail.
#define D_DIM 256
#define S_SYS 16
#define C_CLS 10
#define BLK   1024                 // 16 waves/block, 1 block/CU (LDS-capped)
                                   // NOTE: 1024-thread block => VGPR must stay <=128
#define GRID  256
#define CPB   128                  // samples per chunk (1024 threads / 8 lanes-per-sample)

// LDS W layout:
//   u32 = 2 packed f16 (dims d, d+1)
//   slot(s, c, q, v) = s*S_STR + c*C_STR + q*L_STR + v   (v = 0..15 real, 16..19 pad)
//   v = 2j + t  ->  weight u32 for dims  j*32 + q*4 + 2t .. +1
// Per-lane, per-class: 16 CONTIGUOUS u32 -> 4x ds_read_b128; each 8-lane group's
// starts (20q mod 32) cover all 32 banks exactly once -> conflict-free.
#define L_STR 20
#define C_STR 160      // 8 * L_STR
#define S_STR 1604     // C_CLS * C_STR + 4

typedef __attribute__((ext_vector_type(2))) __fp16 half2v;

__device__ __forceinline__ half2v pack2(float x, float y) {
    return __builtin_amdgcn_cvt_pkrtz(x, y);     // v_cvt_pkrtz_f16_f32
}

__device__ __forceinline__ float fdot2(unsigned w, half2v xp, float c) {
#if __has_builtin(__builtin_amdgcn_fdot2)
    return __builtin_amdgcn_fdot2(__builtin_bit_cast(half2v, w), xp, c, false);
#else
    float d;
    unsigned xu = __builtin_bit_cast(unsigned, xp);
    asm("v_dot2_f32_f16 %0, %1, %2, %3" : "=v"(d) : "v"(w), "v"(xu), "v"(c));
    return d;
#endif
}

__device__ __forceinline__ void load_x(float4 xb[8], const float* __restrict__ x,
                                       long i, int n, int q) {
    const long r = (i < n) ? i : (long)(n - 1);           // clamp (store is masked)
    const float4* p = (const float4*)(x + r * D_DIM) + q; // dims j*32 + q*4 .. +3
    #pragma unroll
    for (int j = 0; j < 8; ++j) xb[j] = p[j * 8];
}

__device__ __forceinline__ int load_sid(const int* __restrict__ sid, long i, int n) {
    return sid[(i < n) ? i : (long)(n - 1)] & (S_SYS - 1);
}

__device__ __forceinline__ void step_compute(const float4 xb[8], long i, int n, int q, int s,
                                             const unsigned* __restrict__ Wl,
                                             const float* __restrict__ bl,
                                             float* __restrict__ out) {
    const unsigned* wp = Wl + (unsigned)s * S_STR + (unsigned)q * L_STR;

    // pack this sample's 32 dims once: xp[2j] = (x.j0, x.j1), xp[2j+1] = (x.j2, x.j3)
    half2v xp[16];
    #pragma unroll
    for (int j = 0; j < 8; ++j) {
        xp[2 * j]     = pack2(xb[j].x, xb[j].y);
        xp[2 * j + 1] = pack2(xb[j].z, xb[j].w);
    }

    float acc[C_CLS];
    #pragma unroll
    for (int c = 0; c < C_CLS; ++c) {
        float a = 0.f;
        #pragma unroll
        for (int k = 0; k < 4; ++k) {                     // uint4 = slots v=4k..4k+3
            const uint4 wv = *(const uint4*)&wp[c * C_STR + 4 * k];
            a = fdot2(wv.x, xp[4 * k + 0], a);
            a = fdot2(wv.y, xp[4 * k + 1], a);
            a = fdot2(wv.z, xp[4 * k + 2], a);
            a = fdot2(wv.w, xp[4 * k + 3], a);
        }
        acc[c] = a;
    }

    // all-reduce each class within the 8-lane group (xor 1,2,4 stay in-group)
    float v0 = 0.f, v1 = 0.f;
    #pragma unroll
    for (int c = 0; c < C_CLS; ++c) {
        float r = acc[c];
        r += __shfl_xor(r, 1);
        r += __shfl_xor(r, 2);
        r += __shfl_xor(r, 4);
        if (c == q)     v0 = r;   // compile-time c, runtime compare (no scratch)
        if (c == 8 + q) v1 = r;
    }
    if (i < n) {
        float* op = out + i * C_CLS;
        op[q] = v0 + bl[s * C_CLS + q];
        if (q < 2) op[8 + q] = v1 + bl[s * C_CLS + 8 + q];
    }
}

__global__ __launch_bounds__(BLK) void mainf_k(const float* __restrict__ x,
                                               const int* __restrict__ sid,
                                               const float* __restrict__ W,
                                               const float* __restrict__ b,
                                               float* __restrict__ out, int n) {
    __shared__ unsigned Wl[S_SYS * S_STR];    // 102,656 B
    __shared__ float    bl[S_SYS * C_CLS];    // 640 B

    const int tid = threadIdx.x;
    const int nch = (n + CPB - 1) / CPB;
    const int cpb = (nch + (int)gridDim.x - 1) / (int)gridDim.x;  // chunks per block
    const int c0 = (int)blockIdx.x * cpb;
    const int c1 = (c0 + cpb < nch) ? (c0 + cpb) : nch;
    if (c0 >= c1) return;                     // whole block exits (before any sync)

    // ---- stage all 16 systems' W (f32 -> packed f16 pairs, RTZ), permuted ----
    const float2* __restrict__ Wg = (const float2*)W;   // pair-index: sc*128 + j*16 + q*2 + t
    for (int u = tid; u < S_SYS * C_CLS * 8 * 16; u += BLK) {   // 20480 real slots
        const int v  = u & 15;
        const int q  = (u >> 4) & 7;
        const int sc = u >> 7;                 // s*10 + c
        const int j  = v >> 1, t = v & 1;
        const float2 f = Wg[(size_t)sc * 128 + j * 16 + q * 2 + t];
        const int s = sc / C_CLS, c = sc - s * C_CLS;
        Wl[s * S_STR + c * C_STR + q * L_STR + v] =
            __builtin_bit_cast(unsigned, pack2(f.x, f.y));
    }
    if (tid < S_SYS * C_CLS) bl[tid] = b[tid];
    __syncthreads();

    const int g = tid >> 3;                   // group (0..127) = sample within chunk
    const int q = tid & 7;                    // lane within group

    // ---- 2-deep pipeline; sid prefetched WITH x (keeps vmcnt queue pure-prefetch) ----
    float4 A[8], Bf[8];
    int ch = c0;
    long iA = (long)ch * CPB + g;
    load_x(A, x, iA, n, q);
    int sA = load_sid(sid, iA, n);
    while (true) {
        const int chB = ch + 1;
        const bool vB = (chB < c1);
        const long iB = (long)chB * CPB + g;
        int sB = 0;
        if (vB) { load_x(Bf, x, iB, n, q); sB = load_sid(sid, iB, n); }
        step_compute(A, iA, n, q, sA, Wl, bl, out);
        if (!vB) break;

        const int chA2 = chB + 1;
        const bool vA = (chA2 < c1);
        const long iA2 = (long)chA2 * CPB + g;
        if (vA) { load_x(A, x, iA2, n, q); sA = load_sid(sid, iA2, n); }
        step_compute(Bf, iB, n, q, sB, Wl, bl, out);
        if (!vA) break;
        ch = chA2; iA = iA2;
    }
}

extern "C" void kernel_launch(void* const* d_in, const int* in_sizes, int n_in,
                              void* d_out, int out_size, void* d_ws, size_t ws_size,
                              hipStream_t stream) {
    const float* x = (const float*)d_in[0];
    const int* sid = (const int*)d_in[1];
    const float* W = (const float*)d_in[2];
    const float* b = (const float*)d_in[3];
    float* out = (float*)d_out;
    const int n = in_sizes[1];   // B

    mainf_k<<<GRID, BLK, 0, stream>>>(x, sid, W, b, out, n);
}